// Round 4
// baseline (18.242 us; speedup 1.0000x reference)
//
#include <hip/hip_runtime.h>
#include <math.h>

// Problem constants (B=2, N_RES=512, N_ATOMS=4)
#define NPTS    2048                    // points per batch
#define THREADS 256
#define IBLOCKS 16                      // 4096 i-points / 256 threads
#define JCHUNKS 64
#define JLEN    (NPTS / JCHUNKS)        // 32 j-iterations per thread
#define NBLOCKS (IBLOCKS * JCHUNKS)     // 1024 producer blocks
#define MAGIC   0xDEADBEEFu

__global__ __launch_bounds__(THREADS) void fused_oneshot_kernel(
    const float* __restrict__ pred, const float* __restrict__ nat,
    const int* __restrict__ mask, float* __restrict__ ws_val,
    unsigned int* __restrict__ ws_tag, float* __restrict__ out, float inv_d0)
{
    __shared__ float red[THREADS / 64];
    __shared__ float aux0[THREADS / 64], aux1[THREADS / 64];

    const int bid  = blockIdx.x;
    const int tid  = threadIdx.x;
    const int lane = tid & 63;
    const int wid  = tid >> 6;

    if (bid < NBLOCKS) {
        // ---------------- producer: one (i-group, j-chunk) tile ----------------
        const int chunk = bid >> 4;                  // 0..63, block-uniform
        const int ig    = bid & (IBLOCKS - 1);       // 0..15
        const int b     = ig >> 3;                   // block-uniform batch
        const int i     = (ig & 7) * THREADS + tid;

        const float* __restrict__ pb = pred + (size_t)(b * NPTS * 3);
        const float* __restrict__ nb = nat  + (size_t)(b * NPTS * 3);
        const int*   __restrict__ mb = mask + b * NPTS;

        const float pix = pb[i*3+0], piy = pb[i*3+1], piz = pb[i*3+2];
        const float nix = nb[i*3+0], niy = nb[i*3+1], niz = nb[i*3+2];
        const int   mi  = mb[i];

        float acc = 0.0f;
        const int j0 = chunk * JLEN;
        #pragma unroll 8
        for (int jj = 0; jj < JLEN; ++jj) {
            const int j = j0 + jj;                   // block-uniform address stream
            const float dx = pix - pb[j*3+0];
            const float dy = piy - pb[j*3+1];
            const float dz = piz - pb[j*3+2];
            const float pd = __builtin_amdgcn_sqrtf(dx*dx + dy*dy + dz*dz);
            const float ex = nix - nb[j*3+0];
            const float ey = niy - nb[j*3+1];
            const float ez = niz - nb[j*3+2];
            const float nd = __builtin_amdgcn_sqrtf(ex*ex + ey*ey + ez*ez);
            const float t    = (pd - nd) * inv_d0;
            const float prox = __builtin_amdgcn_rcpf(1.0f + t*t);
            acc += (mb[j] != 0) ? prox : 0.0f;
        }
        if (mi == 0) acc = 0.0f;

        for (int off = 32; off > 0; off >>= 1)
            acc += __shfl_down(acc, off, 64);
        if (lane == 0) red[wid] = acc;
        __syncthreads();
        if (tid == 0) {
            const float p = red[0] + red[1] + red[2] + red[3];
            // value (relaxed) then tag (release): tag validates the pair.
            __hip_atomic_store(&ws_val[bid], p,
                               __ATOMIC_RELAXED, __HIP_MEMORY_SCOPE_AGENT);
            __hip_atomic_store(&ws_tag[bid], __float_as_uint(p) ^ MAGIC,
                               __ATOMIC_RELEASE, __HIP_MEMORY_SCOPE_AGENT);
        }
    } else {
        // ---------------- finalizer: counts + tagged-spin reduce ----------------
        // mask popcount first (overlaps with producers running)
        int l0 = 0, l1 = 0;
        #pragma unroll
        for (int k = tid; k < NPTS; k += THREADS) {
            l0 += (mask[k]        != 0);
            l1 += (mask[NPTS + k] != 0);
        }

        // gather the 1024 tagged partials (4 slots per thread)
        float s = 0.0f;
        #pragma unroll
        for (int q = 0; q < NBLOCKS / THREADS; ++q) {
            const int idx = tid + q * THREADS;
            unsigned int t; float v;
            do {
                t = __hip_atomic_load(&ws_tag[idx],
                                      __ATOMIC_ACQUIRE, __HIP_MEMORY_SCOPE_AGENT);
                v = __hip_atomic_load(&ws_val[idx],
                                      __ATOMIC_RELAXED, __HIP_MEMORY_SCOPE_AGENT);
            } while ((__float_as_uint(v) ^ MAGIC) != t);
            s += v;
        }

        float f0 = (float)l0, f1 = (float)l1;
        for (int off = 32; off > 0; off >>= 1) {
            s  += __shfl_down(s,  off, 64);
            f0 += __shfl_down(f0, off, 64);
            f1 += __shfl_down(f1, off, 64);
        }
        if (lane == 0) { red[wid] = s; aux0[wid] = f0; aux1[wid] = f1; }
        __syncthreads();
        if (tid == 0) {
            const float S  = red[0]  + red[1]  + red[2]  + red[3];
            const float C0 = aux0[0] + aux0[1] + aux0[2] + aux0[3];
            const float C1 = aux1[0] + aux1[1] + aux1[2] + aux1[3];
            out[0] = -S / (C0 * C0 + C1 * C1);
        }
    }
}

extern "C" void kernel_launch(void* const* d_in, const int* in_sizes, int n_in,
                              void* d_out, int out_size, void* d_ws, size_t ws_size,
                              hipStream_t stream) {
    const float* pred = (const float*)d_in[0];
    const float* nat  = (const float*)d_in[1];
    const int*   mask = (const int*)d_in[2];
    float* out = (float*)d_out;
    float*        ws_val = (float*)d_ws;
    unsigned int* ws_tag = (unsigned int*)((char*)d_ws + NBLOCKS * sizeof(float));

    // d0 = 1.24 * (512 - 15)^(1/3) - 1.8  (host-side pure math, capture-safe)
    const double d0 = 1.24 * cbrt(512.0 - 15.0) - 1.8;
    const float inv_d0 = (float)(1.0 / d0);

    fused_oneshot_kernel<<<NBLOCKS + 1, THREADS, 0, stream>>>(
        pred, nat, mask, ws_val, ws_tag, out, inv_d0);
}

// Round 5
// 12.818 us; speedup vs baseline: 1.4231x; 1.4231x over previous
//
#include <hip/hip_runtime.h>
#include <math.h>

// Problem constants (B=2, N_RES=512, N_ATOMS=4)
#define NPTS    2048                    // points per batch
#define THREADS 256
#define IBLOCKS 16                      // 4096 i-points / 256 threads
#define JCHUNKS 64
#define JLEN    (NPTS / JCHUNKS)        // 32 j-iterations per thread
#define NBLOCKS (IBLOCKS * JCHUNKS)     // 1024 producer blocks
#define MAGIC   0xDEADBEEFu

typedef unsigned long long u64;

__device__ __forceinline__ bool pkt_ok(u64 v) {
    return (unsigned int)(v >> 32) == (((unsigned int)v) ^ MAGIC);
}

__global__ __launch_bounds__(THREADS) void fused_oneshot_kernel(
    const float* __restrict__ pred, const float* __restrict__ nat,
    const int* __restrict__ mask, u64* __restrict__ ws_pkt,
    float* __restrict__ out, float inv_d0)
{
    __shared__ float red[THREADS / 64];
    __shared__ float aux0[THREADS / 64], aux1[THREADS / 64];

    const int bid  = blockIdx.x;
    const int tid  = threadIdx.x;
    const int lane = tid & 63;
    const int wid  = tid >> 6;

    if (bid < NBLOCKS) {
        // ---------------- producer: one (i-group, j-chunk) tile ----------------
        const int chunk = bid >> 4;                  // 0..63, block-uniform
        const int ig    = bid & (IBLOCKS - 1);       // 0..15
        const int b     = ig >> 3;                   // block-uniform batch
        const int i     = (ig & 7) * THREADS + tid;

        const float* __restrict__ pb = pred + (size_t)(b * NPTS * 3);
        const float* __restrict__ nb = nat  + (size_t)(b * NPTS * 3);
        const int*   __restrict__ mb = mask + b * NPTS;

        const float pix = pb[i*3+0], piy = pb[i*3+1], piz = pb[i*3+2];
        const float nix = nb[i*3+0], niy = nb[i*3+1], niz = nb[i*3+2];
        const int   mi  = mb[i];

        float acc = 0.0f;
        const int j0 = chunk * JLEN;
        #pragma unroll 8
        for (int jj = 0; jj < JLEN; ++jj) {
            const int j = j0 + jj;                   // block-uniform address stream
            const float dx = pix - pb[j*3+0];
            const float dy = piy - pb[j*3+1];
            const float dz = piz - pb[j*3+2];
            const float pd = __builtin_amdgcn_sqrtf(dx*dx + dy*dy + dz*dz);
            const float ex = nix - nb[j*3+0];
            const float ey = niy - nb[j*3+1];
            const float ez = niz - nb[j*3+2];
            const float nd = __builtin_amdgcn_sqrtf(ex*ex + ey*ey + ez*ez);
            const float t    = (pd - nd) * inv_d0;
            const float prox = __builtin_amdgcn_rcpf(1.0f + t*t);
            acc += (mb[j] != 0) ? prox : 0.0f;
        }
        if (mi == 0) acc = 0.0f;

        for (int off = 32; off > 0; off >>= 1)
            acc += __shfl_down(acc, off, 64);
        if (lane == 0) red[wid] = acc;
        __syncthreads();
        if (tid == 0) {
            const float p = red[0] + red[1] + red[2] + red[3];
            const unsigned int pv = __float_as_uint(p);
            const u64 pkt = ((u64)(pv ^ MAGIC) << 32) | (u64)pv;
            // single relaxed 64-bit atomic: tag+value consistent by construction,
            // no release fence -> no L2 writeback per block.
            __hip_atomic_store(&ws_pkt[bid], pkt,
                               __ATOMIC_RELAXED, __HIP_MEMORY_SCOPE_AGENT);
        }
    } else {
        // ---------------- finalizer: counts + packed-tag spin reduce ------------
        // mask popcount first (overlaps with producers running)
        int l0 = 0, l1 = 0;
        #pragma unroll
        for (int k = tid; k < NPTS; k += THREADS) {
            l0 += (mask[k]        != 0);
            l1 += (mask[NPTS + k] != 0);
        }

        // 4 slots/thread; keep all 4 loads in flight per retry round
        u64 v0, v1, v2, v3;
        do {
            v0 = __hip_atomic_load(&ws_pkt[tid      ], __ATOMIC_RELAXED, __HIP_MEMORY_SCOPE_AGENT);
            v1 = __hip_atomic_load(&ws_pkt[tid + 256], __ATOMIC_RELAXED, __HIP_MEMORY_SCOPE_AGENT);
            v2 = __hip_atomic_load(&ws_pkt[tid + 512], __ATOMIC_RELAXED, __HIP_MEMORY_SCOPE_AGENT);
            v3 = __hip_atomic_load(&ws_pkt[tid + 768], __ATOMIC_RELAXED, __HIP_MEMORY_SCOPE_AGENT);
        } while (!(pkt_ok(v0) && pkt_ok(v1) && pkt_ok(v2) && pkt_ok(v3)));

        float s = __uint_as_float((unsigned int)v0) + __uint_as_float((unsigned int)v1)
                + __uint_as_float((unsigned int)v2) + __uint_as_float((unsigned int)v3);

        float f0 = (float)l0, f1 = (float)l1;
        for (int off = 32; off > 0; off >>= 1) {
            s  += __shfl_down(s,  off, 64);
            f0 += __shfl_down(f0, off, 64);
            f1 += __shfl_down(f1, off, 64);
        }
        if (lane == 0) { red[wid] = s; aux0[wid] = f0; aux1[wid] = f1; }
        __syncthreads();
        if (tid == 0) {
            const float S  = red[0]  + red[1]  + red[2]  + red[3];
            const float C0 = aux0[0] + aux0[1] + aux0[2] + aux0[3];
            const float C1 = aux1[0] + aux1[1] + aux1[2] + aux1[3];
            out[0] = -S / (C0 * C0 + C1 * C1);
        }
    }
}

extern "C" void kernel_launch(void* const* d_in, const int* in_sizes, int n_in,
                              void* d_out, int out_size, void* d_ws, size_t ws_size,
                              hipStream_t stream) {
    const float* pred = (const float*)d_in[0];
    const float* nat  = (const float*)d_in[1];
    const int*   mask = (const int*)d_in[2];
    float* out = (float*)d_out;
    u64*   ws_pkt = (u64*)d_ws;

    // d0 = 1.24 * (512 - 15)^(1/3) - 1.8  (host-side pure math, capture-safe)
    const double d0 = 1.24 * cbrt(512.0 - 15.0) - 1.8;
    const float inv_d0 = (float)(1.0 / d0);

    fused_oneshot_kernel<<<NBLOCKS + 1, THREADS, 0, stream>>>(
        pred, nat, mask, ws_pkt, out, inv_d0);
}

// Round 6
// 11.191 us; speedup vs baseline: 1.6301x; 1.1454x over previous
//
#include <hip/hip_runtime.h>
#include <math.h>

// Problem constants (B=2, N_RES=512, N_ATOMS=4)
#define NPTS    2048
#define THREADS 512
#define PB      256                  // producer blocks (128 per batch)
#define KPB     8                    // circulant offsets per producer block
#define NS      (NPTS / THREADS)     // 4 i-subrows per thread
#define ARR     2056                 // padded SoA array length (2048 + KPB)
#define MAGIC   0xDEADBEEFu

typedef unsigned long long u64;

__device__ __forceinline__ bool pkt_ok(u64 v) {
    return (unsigned int)(v >> 32) == (((unsigned int)v) ^ MAGIC);
}

// Symmetry: total = 2*sum_{k=1..1023} T_k + T_1024 + diag, T_k = sum_i prox(i, i+k mod N)
__global__ __launch_bounds__(THREADS) void fused_sym_kernel(
    const float* __restrict__ pred, const float* __restrict__ nat,
    const int* __restrict__ mask, u64* __restrict__ ws_pkt,
    float* __restrict__ out, float inv_d0)
{
    __shared__ float lds[7 * ARR];       // SoA: px,py,pz,nx,ny,nz,m (padded +8)
    __shared__ float red[THREADS / 64];

    const int bid  = blockIdx.x;
    const int tid  = threadIdx.x;
    const int lane = tid & 63;
    const int wid  = tid >> 6;

    if (bid < PB) {
        // ---------------- producer ----------------
        const int b   = bid >> 7;          // batch
        const int bib = bid & 127;         // block-in-batch
        const int k0  = 1 + bib * KPB;     // offsets k0..k0+7 (last block hits k=1024)

        const float* __restrict__ pb = pred + (size_t)(b * NPTS * 3);
        const float* __restrict__ nb = nat  + (size_t)(b * NPTS * 3);
        const int*   __restrict__ mb = mask + b * NPTS;

        // stage batch into LDS, SoA layout lds[c*ARR + pt]
        #pragma unroll
        for (int r = 0; r < 12; ++r) {
            const int idx = r * THREADS + tid;       // 0..6143, coalesced
            const int pt  = idx / 3;
            const int c   = idx - 3 * pt;
            lds[c * ARR + pt]       = pb[idx];
            lds[(3 + c) * ARR + pt] = nb[idx];
        }
        #pragma unroll
        for (int r = 0; r < 4; ++r) {
            const int p = r * THREADS + tid;
            lds[6 * ARR + p] = (float)(mb[p] != 0);
        }
        __syncthreads();
        if (tid < 7 * KPB) {                         // wrap-pad 8 entries per array
            const int c = tid >> 3, e = tid & 7;
            lds[c * ARR + NPTS + e] = lds[c * ARR + e];
        }
        __syncthreads();

        float acc[KPB] = {0.f, 0.f, 0.f, 0.f, 0.f, 0.f, 0.f, 0.f};
        for (int s = 0; s < NS; ++s) {
            const int   i   = tid + s * THREADS;
            const float pix = lds[0 * ARR + i], piy = lds[1 * ARR + i], piz = lds[2 * ARR + i];
            const float nix = lds[3 * ARR + i], niy = lds[4 * ARR + i], niz = lds[5 * ARR + i];
            const float mi  = lds[6 * ARR + i];
            const int   jb  = (i + k0) & (NPTS - 1);   // base j; +kk stays in pad range
            #pragma unroll
            for (int kk = 0; kk < KPB; ++kk) {
                const int j = jb + kk;
                const float dx = pix - lds[0 * ARR + j];
                const float dy = piy - lds[1 * ARR + j];
                const float dz = piz - lds[2 * ARR + j];
                const float pd = __builtin_amdgcn_sqrtf(dx * dx + dy * dy + dz * dz);
                const float ex = nix - lds[3 * ARR + j];
                const float ey = niy - lds[4 * ARR + j];
                const float ez = niz - lds[5 * ARR + j];
                const float nd = __builtin_amdgcn_sqrtf(ex * ex + ey * ey + ez * ez);
                const float u  = (pd - nd) * inv_d0;
                const float pr = __builtin_amdgcn_rcpf(fmaf(u, u, 1.0f));
                acc[kk] = fmaf(mi * lds[6 * ARR + j], pr, acc[kk]);
            }
        }

        // k = 1024 (only possible at kk==7 of the last block) counts once, not twice
        const float w7 = (bib == 127) ? 0.5f : 1.0f;
        float partial = acc[0] + acc[1] + acc[2] + acc[3]
                      + acc[4] + acc[5] + acc[6] + w7 * acc[7];

        for (int off = 32; off > 0; off >>= 1)
            partial += __shfl_down(partial, off, 64);
        if (lane == 0) red[wid] = partial;
        __syncthreads();
        if (tid == 0) {
            float p = 0.f;
            #pragma unroll
            for (int w = 0; w < THREADS / 64; ++w) p += red[w];
            const unsigned int pv = __float_as_uint(p);
            const u64 pkt = ((u64)(pv ^ MAGIC) << 32) | (u64)pv;
            __hip_atomic_store(&ws_pkt[bid], pkt,
                               __ATOMIC_RELAXED, __HIP_MEMORY_SCOPE_AGENT);
        }
    } else {
        // ---------------- finalizer ----------------
        int l0 = 0, l1 = 0;
        #pragma unroll
        for (int k = tid; k < NPTS; k += THREADS) {
            l0 += (mask[k]        != 0);
            l1 += (mask[NPTS + k] != 0);
        }

        float s = 0.f;
        if (tid < PB) {
            u64 v;
            do {
                v = __hip_atomic_load(&ws_pkt[tid],
                                      __ATOMIC_RELAXED, __HIP_MEMORY_SCOPE_AGENT);
            } while (!pkt_ok(v));
            s = __uint_as_float((unsigned int)v);
        }

        float f0 = (float)l0, f1 = (float)l1;
        for (int off = 32; off > 0; off >>= 1) {
            s  += __shfl_down(s,  off, 64);
            f0 += __shfl_down(f0, off, 64);
            f1 += __shfl_down(f1, off, 64);
        }
        if (lane == 0) { lds[wid] = s; lds[16 + wid] = f0; lds[32 + wid] = f1; }
        __syncthreads();
        if (tid == 0) {
            float S = 0.f, C0 = 0.f, C1 = 0.f;
            #pragma unroll
            for (int w = 0; w < THREADS / 64; ++w) {
                S += lds[w]; C0 += lds[16 + w]; C1 += lds[32 + w];
            }
            // total = 2*S_offdiag_half + diagonal (masked count), normalized by C0^2+C1^2
            out[0] = -(2.0f * S + C0 + C1) / (C0 * C0 + C1 * C1);
        }
    }
}

extern "C" void kernel_launch(void* const* d_in, const int* in_sizes, int n_in,
                              void* d_out, int out_size, void* d_ws, size_t ws_size,
                              hipStream_t stream) {
    const float* pred = (const float*)d_in[0];
    const float* nat  = (const float*)d_in[1];
    const int*   mask = (const int*)d_in[2];
    float* out = (float*)d_out;
    u64*   ws_pkt = (u64*)d_ws;

    // d0 = 1.24 * (512 - 15)^(1/3) - 1.8  (host-side pure math, capture-safe)
    const double d0 = 1.24 * cbrt(512.0 - 15.0) - 1.8;
    const float inv_d0 = (float)(1.0 / d0);

    fused_sym_kernel<<<PB + 1, THREADS, 0, stream>>>(
        pred, nat, mask, ws_pkt, out, inv_d0);
}

// Round 7
// 10.514 us; speedup vs baseline: 1.7349x; 1.0643x over previous
//
#include <hip/hip_runtime.h>
#include <math.h>

// Problem constants (B=2, N_RES=512, N_ATOMS=4)
#define NPTS    2048
#define THREADS 512
#define PB      256                  // producer blocks (128 per batch)
#define KPB     8                    // circulant offsets per producer block
#define NS      4                    // consecutive i's per thread (i = 4*tid+s)
#define WIN     (NS + KPB - 1)       // 11-wide shared j-window per thread
#define ARR     2060                 // padded SoA array length (2048 + 10 pad)
#define MAGIC   0xDEADBEEFu

typedef unsigned long long u64;

__device__ __forceinline__ bool pkt_ok(u64 v) {
    return (unsigned int)(v >> 32) == (((unsigned int)v) ^ MAGIC);
}

// XOR bank-swizzle: bijective within each 32-word block; identity on [2048,2080)
__device__ __forceinline__ int swz(int p) { return p ^ ((p >> 5) & 31); }

// Symmetry: total = 2*sum_{k=1..1023} T_k + T_1024 + diag, T_k = sum_i prox(i, i+k mod N)
__global__ __launch_bounds__(THREADS) void fused_sym_kernel(
    const float* __restrict__ pred, const float* __restrict__ nat,
    const int* __restrict__ mask, u64* __restrict__ ws_pkt,
    float* __restrict__ out, float inv_d0)
{
    __shared__ float lds[7 * ARR];       // SoA: px,py,pz,nx,ny,nz,m (swizzled)
    __shared__ float red[THREADS / 64];

    const int bid  = blockIdx.x;
    const int tid  = threadIdx.x;
    const int lane = tid & 63;
    const int wid  = tid >> 6;

    if (bid < PB) {
        // ---------------- producer ----------------
        const int b   = bid >> 7;          // batch
        const int bib = bid & 127;         // block-in-batch
        const int k0  = 1 + bib * KPB;     // offsets k0..k0+7 (last block hits k=1024)

        const float* __restrict__ pb = pred + (size_t)(b * NPTS * 3);
        const float* __restrict__ nb = nat  + (size_t)(b * NPTS * 3);
        const int*   __restrict__ mb = mask + b * NPTS;

        // stage batch into LDS, swizzled SoA layout lds[c*ARR + swz(pt)]
        #pragma unroll
        for (int r = 0; r < 12; ++r) {
            const int idx = r * THREADS + tid;       // 0..6143, coalesced
            const int pt  = idx / 3;
            const int c   = idx - 3 * pt;
            const int sp  = swz(pt);
            lds[c * ARR + sp]       = pb[idx];
            lds[(3 + c) * ARR + sp] = nb[idx];
        }
        #pragma unroll
        for (int r = 0; r < 4; ++r) {
            const int p = r * THREADS + tid;
            lds[6 * ARR + swz(p)] = (float)(mb[p] != 0);
        }
        __syncthreads();
        if (tid < 7 * (WIN - 1)) {                   // wrap-pad 10 entries per array
            const int c = tid / (WIN - 1), e = tid % (WIN - 1);
            lds[c * ARR + NPTS + e] = lds[c * ARR + e];  // swz(e)==e for e<32
        }
        __syncthreads();

        // hoist this thread's 4 consecutive i-points into registers
        float pix[NS], piy[NS], piz[NS], nix[NS], niy[NS], niz[NS], mi[NS];
        #pragma unroll
        for (int s = 0; s < NS; ++s) {
            const int si = swz(4 * tid + s);
            pix[s] = lds[0 * ARR + si]; piy[s] = lds[1 * ARR + si]; piz[s] = lds[2 * ARR + si];
            nix[s] = lds[3 * ARR + si]; niy[s] = lds[4 * ARR + si]; niz[s] = lds[5 * ARR + si];
            mi[s]  = lds[6 * ARR + si];
        }

        float acc[KPB] = {0.f, 0.f, 0.f, 0.f, 0.f, 0.f, 0.f, 0.f};
        const int jb = (4 * tid + k0) & (NPTS - 1);   // window base; jb+d <= 2057

        #pragma unroll
        for (int d = 0; d < WIN; ++d) {
            const int ji = swz(jb + d);               // identity on pad region
            const float qx = lds[0 * ARR + ji], qy = lds[1 * ARR + ji], qz = lds[2 * ARR + ji];
            const float ox = lds[3 * ARR + ji], oy = lds[4 * ARR + ji], oz = lds[5 * ARR + ji];
            const float mj = lds[6 * ARR + ji];
            const int smin = (d - (KPB - 1)) > 0 ? (d - (KPB - 1)) : 0;
            const int smax = d < (NS - 1) ? d : (NS - 1);
            #pragma unroll
            for (int s = smin; s <= smax; ++s) {      // kk = d - s in [0, KPB)
                const float dx = pix[s] - qx;
                const float dy = piy[s] - qy;
                const float dz = piz[s] - qz;
                const float pd = __builtin_amdgcn_sqrtf(dx * dx + dy * dy + dz * dz);
                const float ex = nix[s] - ox;
                const float ey = niy[s] - oy;
                const float ez = niz[s] - oz;
                const float nd = __builtin_amdgcn_sqrtf(ex * ex + ey * ey + ez * ez);
                const float u  = (pd - nd) * inv_d0;
                const float pr = __builtin_amdgcn_rcpf(fmaf(u, u, 1.0f));
                acc[d - s] = fmaf(mi[s] * mj, pr, acc[d - s]);
            }
        }

        // k = 1024 (kk==7 of the last block) counts once, not twice
        const float w7 = (bib == 127) ? 0.5f : 1.0f;
        float partial = acc[0] + acc[1] + acc[2] + acc[3]
                      + acc[4] + acc[5] + acc[6] + w7 * acc[7];

        for (int off = 32; off > 0; off >>= 1)
            partial += __shfl_down(partial, off, 64);
        if (lane == 0) red[wid] = partial;
        __syncthreads();
        if (tid == 0) {
            float p = 0.f;
            #pragma unroll
            for (int w = 0; w < THREADS / 64; ++w) p += red[w];
            const unsigned int pv = __float_as_uint(p);
            const u64 pkt = ((u64)(pv ^ MAGIC) << 32) | (u64)pv;
            __hip_atomic_store(&ws_pkt[bid], pkt,
                               __ATOMIC_RELAXED, __HIP_MEMORY_SCOPE_AGENT);
        }
    } else {
        // ---------------- finalizer ----------------
        int l0 = 0, l1 = 0;
        #pragma unroll
        for (int k = tid; k < NPTS; k += THREADS) {
            l0 += (mask[k]        != 0);
            l1 += (mask[NPTS + k] != 0);
        }

        float s = 0.f;
        if (tid < PB) {
            u64 v;
            do {
                v = __hip_atomic_load(&ws_pkt[tid],
                                      __ATOMIC_RELAXED, __HIP_MEMORY_SCOPE_AGENT);
            } while (!pkt_ok(v));
            s = __uint_as_float((unsigned int)v);
        }

        float f0 = (float)l0, f1 = (float)l1;
        for (int off = 32; off > 0; off >>= 1) {
            s  += __shfl_down(s,  off, 64);
            f0 += __shfl_down(f0, off, 64);
            f1 += __shfl_down(f1, off, 64);
        }
        if (lane == 0) { lds[wid] = s; lds[16 + wid] = f0; lds[32 + wid] = f1; }
        __syncthreads();
        if (tid == 0) {
            float S = 0.f, C0 = 0.f, C1 = 0.f;
            #pragma unroll
            for (int w = 0; w < THREADS / 64; ++w) {
                S += lds[w]; C0 += lds[16 + w]; C1 += lds[32 + w];
            }
            // total = 2*S_offdiag_half + diagonal (masked count), normalized
            out[0] = -(2.0f * S + C0 + C1) / (C0 * C0 + C1 * C1);
        }
    }
}

extern "C" void kernel_launch(void* const* d_in, const int* in_sizes, int n_in,
                              void* d_out, int out_size, void* d_ws, size_t ws_size,
                              hipStream_t stream) {
    const float* pred = (const float*)d_in[0];
    const float* nat  = (const float*)d_in[1];
    const int*   mask = (const int*)d_in[2];
    float* out = (float*)d_out;
    u64*   ws_pkt = (u64*)d_ws;

    // d0 = 1.24 * (512 - 15)^(1/3) - 1.8  (host-side pure math, capture-safe)
    const double d0 = 1.24 * cbrt(512.0 - 15.0) - 1.8;
    const float inv_d0 = (float)(1.0 / d0);

    fused_sym_kernel<<<PB + 1, THREADS, 0, stream>>>(
        pred, nat, mask, ws_pkt, out, inv_d0);
}